// Round 1
// baseline (345.588 us; speedup 1.0000x reference)
//
#include <hip/hip_runtime.h>
#include <stdint.h>

// Gator: logic-gate network forward, bit-packed over batch.
// B=8192 batches, W0=1024 inputs, R=8 rows x G=1024 gates, out width 9216.
//
// Each block owns 32 batch elements (one uint32 bit-plane per column) and the
// full 9216-column history in LDS (36.8 KB). Rows are sequential within the
// block (__syncthreads between rows); batch slices are fully independent, so
// one fused kernel launch suffices. HBM floor: 33.5 MB read + 302 MB write.

constexpr int B    = 8192;
constexpr int W0   = 1024;
constexpr int R    = 8;
constexpr int G    = 1024;
constexpr int WTOT = W0 + R * G;   // 9216
constexpr int BPB  = 32;           // batch elements (bits) per block

__launch_bounds__(256, 1)
__global__ void gator_fused(const float* __restrict__ x,
                            const float* __restrict__ gates,
                            const int*   __restrict__ choices,
                            float*       __restrict__ out) {
    __shared__ uint32_t cols[WTOT];      // bit b of cols[w] = value of (batch b0+b, col w)

    const int tid  = threadIdx.x;
    const int lane = tid & 63;
    const int wv   = tid >> 6;           // wave id 0..3
    const int b0   = blockIdx.x * BPB;
    const int half = lane >> 5;          // 0: lanes 0-31, 1: lanes 32-63
    const int row  = b0 + (lane & 31);

    // ---- Phase A: pack input x[b0..b0+31][0..1023] into bit columns ----
    // Wave wv covers cols [wv*256, wv*256+256). Per iteration: lanes 0-31 load
    // float4 at col c (batch = bit index), lanes 32-63 at col c+4. Each ballot
    // yields two packed columns (lo32 = col c+j, hi32 = col c+4+j).
    {
        const float4* xrow = (const float4*)(x + (size_t)row * W0);
        for (int it = 0; it < 32; ++it) {
            int c = wv * 256 + it * 8 + half * 4;
            float4 v = xrow[c >> 2];
            unsigned long long m0 = __ballot(v.x != 0.0f);
            unsigned long long m1 = __ballot(v.y != 0.0f);
            unsigned long long m2 = __ballot(v.z != 0.0f);
            unsigned long long m3 = __ballot(v.w != 0.0f);
            if ((lane & 31) == 0) {      // lane 0 writes cols c..c+3, lane 32 writes c+4..c+7
                int s = half * 32;
                cols[c + 0] = (uint32_t)(m0 >> s);
                cols[c + 1] = (uint32_t)(m1 >> s);
                cols[c + 2] = (uint32_t)(m2 >> s);
                cols[c + 3] = (uint32_t)(m3 >> s);
            }
        }
    }
    __syncthreads();

    // ---- Phase B: 8 gate rows, bitwise LUT over 32 batch lanes at once ----
    // idx = x[c0]*2 + x[c1]; LUT select as bitwise mux of the 4 table entries.
    {
        const int2*   ch2 = (const int2*)choices;   // [R*G] pairs
        const float4* g4  = (const float4*)gates;   // [R*G] 4-entry tables
        for (int r = 0; r < R; ++r) {
            for (int g = tid; g < G; g += 256) {
                int2     ch = ch2[r * G + g];
                uint32_t a  = cols[ch.x];
                uint32_t b  = cols[ch.y];
                float4   lt = g4[r * G + g];
                uint32_t o = 0u;
                o |= (lt.x != 0.0f) ? (~a & ~b) : 0u;   // idx 0: a=0,b=0
                o |= (lt.y != 0.0f) ? (~a &  b) : 0u;   // idx 1: a=0,b=1
                o |= (lt.z != 0.0f) ? ( a & ~b) : 0u;   // idx 2: a=1,b=0
                o |= (lt.w != 0.0f) ? ( a &  b) : 0u;   // idx 3: a=1,b=1
                cols[W0 + r * G + g] = o;
            }
            __syncthreads();
        }
    }

    // ---- Phase C: unpack all 9216 columns to float32 rows b0..b0+31 ----
    // Thread t owns cols wbase+4t..+3 (uint4 LDS read); inner loop over the 32
    // batch bits emits one coalesced float4 store per wave-row.
    for (int wbase = 0; wbase < WTOT; wbase += 1024) {
        int w = wbase + tid * 4;
        uint4 c = *(const uint4*)&cols[w];
        float* orow = out + (size_t)b0 * WTOT + w;
        #pragma unroll
        for (int b = 0; b < BPB; ++b) {
            float4 v;
            v.x = (float)((c.x >> b) & 1u);
            v.y = (float)((c.y >> b) & 1u);
            v.z = (float)((c.z >> b) & 1u);
            v.w = (float)((c.w >> b) & 1u);
            *(float4*)(orow + (size_t)b * WTOT) = v;
        }
    }
}

extern "C" void kernel_launch(void* const* d_in, const int* in_sizes, int n_in,
                              void* d_out, int out_size, void* d_ws, size_t ws_size,
                              hipStream_t stream) {
    const float* x       = (const float*)d_in[0];
    const float* gates   = (const float*)d_in[1];
    const int*   choices = (const int*)d_in[2];
    float*       out     = (float*)d_out;

    gator_fused<<<dim3(B / BPB), dim3(256), 0, stream>>>(x, gates, choices, out);
}